// Round 8
// baseline (374.009 us; speedup 1.0000x reference)
//
#include <hip/hip_runtime.h>

// Problem constants (X, Y: (64, 128, 64) fp32)
#define AA   64
#define MM   128
#define DD   64
#define M1   127
#define CSTR 132                 // inc row stride (words); 132%32=4 -> 2-way banks (free)
#define NXY  1024                // XY gram blocks (all 4096 pairs, 4/block)
#define NTRI 544                 // triangle blocks per symmetric gram (a<=b)
#define NBLK (NXY + 2*NTRI)      // 2112
// ws layout: [0,4MB) frag regions {Xhi,Xlo,Yhi,Ylo} each 1MB =
//   path(64) x tile(8) x ks(2) x lane(64) x int4 ; then NBLK partials + ctr.
#define REG_I4 65536             // int4 per 1MB region
#define PART_OFF (4u << 20)

typedef float f32x4 __attribute__((ext_vector_type(4)));
typedef short bf8_t __attribute__((ext_vector_type(8)));

__device__ __forceinline__ unsigned bf16_rne(float v) {
    unsigned u = __float_as_uint(v);
    return (u + 0x7FFFu + ((u >> 16) & 1u)) >> 16;
}
__device__ __forceinline__ float bf16_tof(unsigned h) {
    return __uint_as_float(h << 16);
}

// ---------------------------------------------------------------------------
// prep: build hi/lo bf16 fragments of dX/dY once, in MFMA fragment order.
// A-frag and B-frag layouts coincide (idx16=lane&15, k=(lane>>4)*8+j).
// Row 127 clamped to 126 (as A: never-scanned row; as B: col masked at lane63).
// Block 0 also zeroes the completion counter for sig_pde's last-block fold.
// ---------------------------------------------------------------------------
__global__ __launch_bounds__(256) void prep_frags(const float* __restrict__ X,
                                                  const float* __restrict__ Y,
                                                  int4* __restrict__ frag,
                                                  unsigned* __restrict__ ctr) {
    const int tid = threadIdx.x, lane = tid & 63, w = tid >> 6;
    if (blockIdx.x == 0 && tid == 0) *ctr = 0u;
    const int W    = blockIdx.x * 4 + w;   // 0..1023
    const int inp  = W >> 9;               // 0: X, 1: Y
    const int p    = (W >> 3) & 63;
    const int tile = W & 7;
    const float* S = (inp ? Y : X) + p * (MM * DD);
    int i = tile * 16 + (lane & 15);
    if (i > 126) i = 126;
    const int d0 = (lane >> 4) << 3;

    int4* hi = frag + (inp * 2 + 0) * REG_I4;
    int4* lo = frag + (inp * 2 + 1) * REG_I4;
    const int base = p * 1024 + tile * 128 + lane;

    #pragma unroll
    for (int ks = 0; ks < 2; ++ks) {
        const float* r0 = S + i * DD + ks * 32 + d0;
        const float* r1 = r0 + DD;
        float4 a0 = *(const float4*)r0;
        float4 a1 = *(const float4*)(r0 + 4);
        float4 c0 = *(const float4*)r1;
        float4 c1 = *(const float4*)(r1 + 4);
        float v[8] = {c0.x - a0.x, c0.y - a0.y, c0.z - a0.z, c0.w - a0.w,
                      c1.x - a1.x, c1.y - a1.y, c1.z - a1.z, c1.w - a1.w};
        unsigned hs[8], ls[8];
        #pragma unroll
        for (int e = 0; e < 8; ++e) {
            hs[e] = bf16_rne(v[e]);
            ls[e] = bf16_rne(v[e] - bf16_tof(hs[e]));
        }
        int4 h, l;
        h.x = hs[0] | (hs[1] << 16); h.y = hs[2] | (hs[3] << 16);
        h.z = hs[4] | (hs[5] << 16); h.w = hs[6] | (hs[7] << 16);
        l.x = ls[0] | (ls[1] << 16); l.y = ls[2] | (ls[3] << 16);
        l.z = ls[4] | (ls[5] << 16); l.w = ls[6] | (ls[7] << 16);
        hi[base + ks * 64] = h;
        lo[base + ks * 64] = l;
    }
}

// ---------------------------------------------------------------------------
// PDE kernel. gid < 1024: XY gram (all pairs). Else triangle blocks for
// XX / YY (a<=b; weight 2 off-diag, 1 diag, 0 ragged). Per wave: 8 strips of
// (A prefetch | 48 MFMA | C->LDS | 16 ds_read_b64 -> regs | fused-DPP scan).
// Scan math/order identical to verified R4-R6 recursion. R7 LESSON: CDNA has
// a manual-wait-state hazard "VALU writes VGPR -> VALU DPP reads it: 2 wait
// states"; the hazard recognizer cannot see inside inline asm, so each DPP
// asm statement carries its own leading s_nop 1 (2 wait states). R7 omitted
// them -> stale DPP reads -> NaN.
// Last finishing block folds the partials + msq term into out[0].
// ---------------------------------------------------------------------------
__global__ __launch_bounds__(256, 2)
void sig_pde(const int4* __restrict__ frag, float* __restrict__ partials,
             unsigned* __restrict__ ctr,
             const float* __restrict__ X, const float* __restrict__ Y,
             float* __restrict__ out) {
    const int tid = threadIdx.x, lane = tid & 63, w = tid >> 6;
    const int gid = blockIdx.x;

    int a, b, ain, bin;
    float wgt;
    if (gid < NXY) {
        b = gid >> 4; a = ((gid & 15) << 2) | w;
        ain = 0; bin = 1;
        wgt = -2.0f / 4096.0f;
    } else {
        int t = gid - NXY;
        int inp = 0;
        if (t >= NTRI) { t -= NTRI; inp = 1; }
        int q = (int)((__builtin_sqrtf((float)(2 * t + 1)) - 1.0f) * 0.5f);
        while (2 * (q + 1) * (q + 2) <= t) ++q;
        while (q > 0 && 2 * q * (q + 1) > t) --q;
        int r  = t - 2 * q * (q + 1);
        int i  = r / (q + 1);
        int ag = r - i * (q + 1);
        b = 4 * q + i; a = 4 * ag + w;
        ain = bin = inp;
        wgt = (a < b) ? (2.0f / 4096.0f) : ((a == b) ? (1.0f / 4096.0f) : 0.0f);
    }

    __shared__ int4  Bh[1024], Bl[1024];     // 32 KB B fragments (hi/lo)
    __shared__ float incS[4][16 * CSTR];     // 33 KB per-wave inc strips
    __shared__ float red4[4];
    __shared__ int   amLast;

    // --- stage this block's B fragment set (flat 32 KB copy) --------------
    {
        const int4* Bhg = frag + (bin * 2 + 0) * REG_I4 + b * 1024;
        const int4* Blg = frag + (bin * 2 + 1) * REG_I4 + b * 1024;
        #pragma unroll
        for (int c = 0; c < 4; ++c) {
            int idx = c * 256 + tid;
            Bh[idx] = Bhg[idx];
            Bl[idx] = Blg[idx];
        }
    }
    __syncthreads();

    const int4* Ahg = frag + (ain * 2 + 0) * REG_I4 + a * 1024;
    const int4* Alg = frag + (ain * 2 + 1) * REG_I4 + a * 1024;

    int4 Ah[2], Al[2], Ahn[2], Aln[2];
    Ah[0] = Ahg[lane];      Ah[1] = Ahg[64 + lane];
    Al[0] = Alg[lane];      Al[1] = Alg[64 + lane];

    float k0 = 1.0f, k1 = 1.0f;              // K[2l], K[2l+1] of current row
    float* incW = &incS[w][0];
    const int c2l = lane << 1;
    const int r0w = (lane >> 4) << 2, c0w = lane & 15;

    for (int strip = 0; strip < 8; ++strip) {
        if (strip < 7) {                     // prefetch next strip's A frags
            int off = (strip + 1) * 128 + lane;
            Ahn[0] = Ahg[off]; Ahn[1] = Ahg[off + 64];
            Aln[0] = Alg[off]; Aln[1] = Alg[off + 64];
        }

        f32x4 acc[8];
        #pragma unroll
        for (int t = 0; t < 8; ++t) acc[t] = (f32x4){0.f, 0.f, 0.f, 0.f};
        #pragma unroll
        for (int s = 0; s < 2; ++s) {
            bf8_t ah = __builtin_bit_cast(bf8_t, Ah[s]);
            bf8_t al = __builtin_bit_cast(bf8_t, Al[s]);
            #pragma unroll
            for (int t = 0; t < 8; ++t) {
                int fb = (t * 2 + s) * 64 + lane;
                bf8_t bh = *(const bf8_t*)&Bh[fb];
                bf8_t bl = *(const bf8_t*)&Bl[fb];
                acc[t] = __builtin_amdgcn_mfma_f32_16x16x32_bf16(ah, bh, acc[t], 0, 0, 0);
                acc[t] = __builtin_amdgcn_mfma_f32_16x16x32_bf16(ah, bl, acc[t], 0, 0, 0);
                acc[t] = __builtin_amdgcn_mfma_f32_16x16x32_bf16(al, bh, acc[t], 0, 0, 0);
            }
        }

        // C frags -> per-wave inc strip (2-way bank alias only; free)
        #pragma unroll
        for (int t = 0; t < 8; ++t) {
            float* pb = incW + r0w * CSTR + (t << 4) + c0w;
            pb[0]        = acc[t][0];
            pb[CSTR]     = acc[t][1];
            pb[2 * CSTR] = acc[t][2];
            pb[3 * CSTR] = acc[t][3];
        }

        // hoist the strip's 16 scan rows into regs (one lgkm drain, not 16)
        float2 rowv[16];
        #pragma unroll
        for (int r = 0; r < 16; ++r)
            rowv[r] = *(const float2*)(incW + r * CSTR + c2l);

        // fused-DPP scan. Each DPP carries s_nop 1 (2 wait states) for the
        // CDNA "VALU write -> DPP read" hazard (inline asm is opaque to the
        // compiler's hazard recognizer — omitting these was R7's NaN).
        const int rmax = (strip == 7) ? 15 : 16;
        for (int r = 0; r < rmax; ++r) {
            float s0 = rowv[r].x, s1 = rowv[r].y;
            float kp2;
            asm("s_nop 1\n\t"
                "v_mov_b32_dpp %0, %1 wave_shl:1 row_mask:0xf bank_mask:0xf bound_ctrl:0"
                : "=v"(kp2) : "v"(k0));                      // K[2l+2]
            float e0 = __builtin_fmaf(k0, s0, k1 - k0);      // delta[2l]
            float e1 = __builtin_fmaf(k1, s1, kp2 - k1);     // delta[2l+1]
            e1 = (lane < 63) ? e1 : 0.0f;
            float S = e0 + e1;
            asm("s_nop 1\n\t"
                "v_add_f32_dpp %0, %0, %0 row_shr:1 row_mask:0xf bank_mask:0xf bound_ctrl:0" : "+v"(S));
            asm("s_nop 1\n\t"
                "v_add_f32_dpp %0, %0, %0 row_shr:2 row_mask:0xf bank_mask:0xf bound_ctrl:0" : "+v"(S));
            asm("s_nop 1\n\t"
                "v_add_f32_dpp %0, %0, %0 row_shr:4 row_mask:0xf bank_mask:0xf bound_ctrl:0" : "+v"(S));
            asm("s_nop 1\n\t"
                "v_add_f32_dpp %0, %0, %0 row_shr:8 row_mask:0xf bank_mask:0xf bound_ctrl:0" : "+v"(S));
            asm("s_nop 1\n\t"
                "v_add_f32_dpp %0, %0, %0 row_bcast:15 row_mask:0xa bank_mask:0xf bound_ctrl:0" : "+v"(S));
            asm("s_nop 1\n\t"
                "v_add_f32_dpp %0, %0, %0 row_bcast:31 row_mask:0xc bank_mask:0xf bound_ctrl:0" : "+v"(S));
            float Sp;
            asm("s_nop 1\n\t"
                "v_mov_b32_dpp %0, %1 wave_shr:1 row_mask:0xf bank_mask:0xf bound_ctrl:0"
                : "=v"(Sp) : "v"(S));                        // S_{l-1}
            k0 = 1.0f + Sp;                                  // lane0: Sp=0 -> 1
            k1 = 1.0f + (S - e1);
        }

        Ah[0] = Ahn[0]; Ah[1] = Ahn[1];
        Al[0] = Aln[0]; Al[1] = Aln[1];
    }

    // --- epilogue: per-block partial, last block folds everything ---------
    if (lane == 63) red4[w] = wgt * k1;      // weighted K[127][127]
    __syncthreads();
    if (tid == 0) {
        float s = red4[0] + red4[1] + red4[2] + red4[3];
        __hip_atomic_store(&partials[gid], s, __ATOMIC_RELEASE,
                           __HIP_MEMORY_SCOPE_AGENT);
        unsigned prev = __hip_atomic_fetch_add(ctr, 1u, __ATOMIC_ACQ_REL,
                                               __HIP_MEMORY_SCOPE_AGENT);
        amLast = (prev == NBLK - 1);
    }
    __syncthreads();
    if (amLast) {
        float acc = 0.f;
        for (int e = tid; e < NBLK; e += 256)
            acc += __hip_atomic_load(&partials[e], __ATOMIC_ACQUIRE,
                                     __HIP_MEMORY_SCOPE_AGENT);
        for (int e = tid; e < AA * DD; e += 256) {
            int aa = e >> 6, d = e & 63;
            float df = X[aa * (MM * DD) + d] - Y[aa * (MM * DD) + d];
            acc = __builtin_fmaf(df * df, 1.0f / 4096.0f, acc);
        }
        #pragma unroll
        for (int off = 32; off > 0; off >>= 1) acc += __shfl_down(acc, off);
        __syncthreads();
        if ((tid & 63) == 0) red4[tid >> 6] = acc;
        __syncthreads();
        if (tid == 0) out[0] = red4[0] + red4[1] + red4[2] + red4[3];
    }
}

extern "C" void kernel_launch(void* const* d_in, const int* in_sizes, int n_in,
                              void* d_out, int out_size, void* d_ws, size_t ws_size,
                              hipStream_t stream) {
    const float* X = (const float*)d_in[0];
    const float* Y = (const float*)d_in[1];
    float* out = (float*)d_out;
    int4*  frag = (int4*)d_ws;
    float* partials = (float*)((char*)d_ws + PART_OFF);
    unsigned* ctr = (unsigned*)((char*)d_ws + PART_OFF + NBLK * sizeof(float));

    hipLaunchKernelGGL(prep_frags, dim3(256), dim3(256), 0, stream, X, Y, frag, ctr);
    hipLaunchKernelGGL(sig_pde, dim3(NBLK), dim3(256), 0, stream,
                       frag, partials, ctr, X, Y, out);
}

// Round 9
// 215.951 us; speedup vs baseline: 1.7319x; 1.7319x over previous
//
#include <hip/hip_runtime.h>

// Problem constants (X, Y: (64, 128, 64) fp32)
#define AA   64
#define MM   128
#define DD   64
#define M1   127
#define CSTR 132                 // inc row stride (words); 132%32=4 -> 2-way banks (free)
#define NXY  1024                // XY gram blocks (all 4096 pairs, 4/block)
#define NTRI 544                 // triangle blocks per symmetric gram (a<=b)
#define NBLK (NXY + 2*NTRI)      // 2112
// ws layout: [0,4MB) frag regions {Xhi,Xlo,Yhi,Ylo} each 1MB =
//   path(64) x tile(8) x ks(2) x lane(64) x int4 ; then NBLK partials + ctr.
#define REG_I4 65536             // int4 per 1MB region
#define PART_OFF (4u << 20)

typedef float f32x4 __attribute__((ext_vector_type(4)));
typedef short bf8_t __attribute__((ext_vector_type(8)));

__device__ __forceinline__ unsigned bf16_rne(float v) {
    unsigned u = __float_as_uint(v);
    return (u + 0x7FFFu + ((u >> 16) & 1u)) >> 16;
}
__device__ __forceinline__ float bf16_tof(unsigned h) {
    return __uint_as_float(h << 16);
}

// ---------------------------------------------------------------------------
// prep: build hi/lo bf16 fragments of dX/dY once, in MFMA fragment order.
// A-frag and B-frag layouts coincide (idx16=lane&15, k=(lane>>4)*8+j).
// Row 127 clamped to 126 (as A: never-scanned row; as B: col masked at lane63).
// Block 0 also zeroes the completion counter for sig_pde's last-block fold.
// ---------------------------------------------------------------------------
__global__ __launch_bounds__(256) void prep_frags(const float* __restrict__ X,
                                                  const float* __restrict__ Y,
                                                  int4* __restrict__ frag,
                                                  unsigned* __restrict__ ctr) {
    const int tid = threadIdx.x, lane = tid & 63, w = tid >> 6;
    if (blockIdx.x == 0 && tid == 0) *ctr = 0u;
    const int W    = blockIdx.x * 4 + w;   // 0..1023
    const int inp  = W >> 9;               // 0: X, 1: Y
    const int p    = (W >> 3) & 63;
    const int tile = W & 7;
    const float* S = (inp ? Y : X) + p * (MM * DD);
    int i = tile * 16 + (lane & 15);
    if (i > 126) i = 126;
    const int d0 = (lane >> 4) << 3;

    int4* hi = frag + (inp * 2 + 0) * REG_I4;
    int4* lo = frag + (inp * 2 + 1) * REG_I4;
    const int base = p * 1024 + tile * 128 + lane;

    #pragma unroll
    for (int ks = 0; ks < 2; ++ks) {
        const float* r0 = S + i * DD + ks * 32 + d0;
        const float* r1 = r0 + DD;
        float4 a0 = *(const float4*)r0;
        float4 a1 = *(const float4*)(r0 + 4);
        float4 c0 = *(const float4*)r1;
        float4 c1 = *(const float4*)(r1 + 4);
        float v[8] = {c0.x - a0.x, c0.y - a0.y, c0.z - a0.z, c0.w - a0.w,
                      c1.x - a1.x, c1.y - a1.y, c1.z - a1.z, c1.w - a1.w};
        unsigned hs[8], ls[8];
        #pragma unroll
        for (int e = 0; e < 8; ++e) {
            hs[e] = bf16_rne(v[e]);
            ls[e] = bf16_rne(v[e] - bf16_tof(hs[e]));
        }
        int4 h, l;
        h.x = hs[0] | (hs[1] << 16); h.y = hs[2] | (hs[3] << 16);
        h.z = hs[4] | (hs[5] << 16); h.w = hs[6] | (hs[7] << 16);
        l.x = ls[0] | (ls[1] << 16); l.y = ls[2] | (ls[3] << 16);
        l.z = ls[4] | (ls[5] << 16); l.w = ls[6] | (ls[7] << 16);
        hi[base + ks * 64] = h;
        lo[base + ks * 64] = l;
    }
}

// ---------------------------------------------------------------------------
// PDE kernel. gid < 1024: XY gram (all pairs). Else triangle blocks for
// XX / YY (a<=b; weight 2 off-diag, 1 diag, 0 ragged). Per wave: 8 strips of
// (A prefetch | 48 MFMA | C->LDS | per-row ds_read_b64 + fused-DPP scan).
// R8 LESSON: hoisting the 16 rows into a reg array indexed by a runtime-
// bounded loop sent the array to scratch (300 MB HBM writes, 333 us) — the
// scan reads LDS directly instead (dynamic LDS indexing is fine; R6: 106 us).
// DPP hazard: each DPP asm carries s_nop 1 ("VALU write -> DPP read" needs 2
// wait states; inline asm is opaque to the hazard recognizer — R7's NaN).
// Last finishing block folds the partials + msq term into out[0].
// ---------------------------------------------------------------------------
__global__ __launch_bounds__(256, 2)
void sig_pde(const int4* __restrict__ frag, float* __restrict__ partials,
             unsigned* __restrict__ ctr,
             const float* __restrict__ X, const float* __restrict__ Y,
             float* __restrict__ out) {
    const int tid = threadIdx.x, lane = tid & 63, w = tid >> 6;
    const int gid = blockIdx.x;

    int a, b, ain, bin;
    float wgt;
    if (gid < NXY) {
        b = gid >> 4; a = ((gid & 15) << 2) | w;
        ain = 0; bin = 1;
        wgt = -2.0f / 4096.0f;
    } else {
        int t = gid - NXY;
        int inp = 0;
        if (t >= NTRI) { t -= NTRI; inp = 1; }
        int q = (int)((__builtin_sqrtf((float)(2 * t + 1)) - 1.0f) * 0.5f);
        while (2 * (q + 1) * (q + 2) <= t) ++q;
        while (q > 0 && 2 * q * (q + 1) > t) --q;
        int r  = t - 2 * q * (q + 1);
        int i  = r / (q + 1);
        int ag = r - i * (q + 1);
        b = 4 * q + i; a = 4 * ag + w;
        ain = bin = inp;
        wgt = (a < b) ? (2.0f / 4096.0f) : ((a == b) ? (1.0f / 4096.0f) : 0.0f);
    }

    __shared__ int4  Bh[1024], Bl[1024];     // 32 KB B fragments (hi/lo)
    __shared__ float incS[4][16 * CSTR];     // 33 KB per-wave inc strips
    __shared__ float red4[4];
    __shared__ int   amLast;

    // --- stage this block's B fragment set (flat 32 KB copy) --------------
    {
        const int4* Bhg = frag + (bin * 2 + 0) * REG_I4 + b * 1024;
        const int4* Blg = frag + (bin * 2 + 1) * REG_I4 + b * 1024;
        #pragma unroll
        for (int c = 0; c < 4; ++c) {
            int idx = c * 256 + tid;
            Bh[idx] = Bhg[idx];
            Bl[idx] = Blg[idx];
        }
    }
    __syncthreads();

    const int4* Ahg = frag + (ain * 2 + 0) * REG_I4 + a * 1024;
    const int4* Alg = frag + (ain * 2 + 1) * REG_I4 + a * 1024;

    int4 Ah[2], Al[2], Ahn[2], Aln[2];
    Ah[0] = Ahg[lane];      Ah[1] = Ahg[64 + lane];
    Al[0] = Alg[lane];      Al[1] = Alg[64 + lane];

    float k0 = 1.0f, k1 = 1.0f;              // K[2l], K[2l+1] of current row
    float* incW = &incS[w][0];
    const int c2l = lane << 1;
    const int r0w = (lane >> 4) << 2, c0w = lane & 15;

    for (int strip = 0; strip < 8; ++strip) {
        if (strip < 7) {                     // prefetch next strip's A frags
            int off = (strip + 1) * 128 + lane;
            Ahn[0] = Ahg[off]; Ahn[1] = Ahg[off + 64];
            Aln[0] = Alg[off]; Aln[1] = Alg[off + 64];
        }

        f32x4 acc[8];
        #pragma unroll
        for (int t = 0; t < 8; ++t) acc[t] = (f32x4){0.f, 0.f, 0.f, 0.f};
        #pragma unroll
        for (int s = 0; s < 2; ++s) {
            bf8_t ah = __builtin_bit_cast(bf8_t, Ah[s]);
            bf8_t al = __builtin_bit_cast(bf8_t, Al[s]);
            #pragma unroll
            for (int t = 0; t < 8; ++t) {
                int fb = (t * 2 + s) * 64 + lane;
                bf8_t bh = *(const bf8_t*)&Bh[fb];
                bf8_t bl = *(const bf8_t*)&Bl[fb];
                acc[t] = __builtin_amdgcn_mfma_f32_16x16x32_bf16(ah, bh, acc[t], 0, 0, 0);
                acc[t] = __builtin_amdgcn_mfma_f32_16x16x32_bf16(ah, bl, acc[t], 0, 0, 0);
                acc[t] = __builtin_amdgcn_mfma_f32_16x16x32_bf16(al, bh, acc[t], 0, 0, 0);
            }
        }

        // C frags -> per-wave inc strip (2-way bank alias only; free)
        #pragma unroll
        for (int t = 0; t < 8; ++t) {
            float* pb = incW + r0w * CSTR + (t << 4) + c0w;
            pb[0]        = acc[t][0];
            pb[CSTR]     = acc[t][1];
            pb[2 * CSTR] = acc[t][2];
            pb[3 * CSTR] = acc[t][3];
        }

        // fused-DPP scan, reading each row directly from LDS (no reg array).
        const int rmax = (strip == 7) ? 15 : 16;
        for (int r = 0; r < rmax; ++r) {
            float2 sv = *(const float2*)(incW + r * CSTR + c2l);
            float s0 = sv.x, s1 = sv.y;
            float kp2;
            asm("s_nop 1\n\t"
                "v_mov_b32_dpp %0, %1 wave_shl:1 row_mask:0xf bank_mask:0xf bound_ctrl:0"
                : "=v"(kp2) : "v"(k0));                      // K[2l+2]
            float e0 = __builtin_fmaf(k0, s0, k1 - k0);      // delta[2l]
            float e1 = __builtin_fmaf(k1, s1, kp2 - k1);     // delta[2l+1]
            e1 = (lane < 63) ? e1 : 0.0f;
            float S = e0 + e1;
            asm("s_nop 1\n\t"
                "v_add_f32_dpp %0, %0, %0 row_shr:1 row_mask:0xf bank_mask:0xf bound_ctrl:0" : "+v"(S));
            asm("s_nop 1\n\t"
                "v_add_f32_dpp %0, %0, %0 row_shr:2 row_mask:0xf bank_mask:0xf bound_ctrl:0" : "+v"(S));
            asm("s_nop 1\n\t"
                "v_add_f32_dpp %0, %0, %0 row_shr:4 row_mask:0xf bank_mask:0xf bound_ctrl:0" : "+v"(S));
            asm("s_nop 1\n\t"
                "v_add_f32_dpp %0, %0, %0 row_shr:8 row_mask:0xf bank_mask:0xf bound_ctrl:0" : "+v"(S));
            asm("s_nop 1\n\t"
                "v_add_f32_dpp %0, %0, %0 row_bcast:15 row_mask:0xa bank_mask:0xf bound_ctrl:0" : "+v"(S));
            asm("s_nop 1\n\t"
                "v_add_f32_dpp %0, %0, %0 row_bcast:31 row_mask:0xc bank_mask:0xf bound_ctrl:0" : "+v"(S));
            float Sp;
            asm("s_nop 1\n\t"
                "v_mov_b32_dpp %0, %1 wave_shr:1 row_mask:0xf bank_mask:0xf bound_ctrl:0"
                : "=v"(Sp) : "v"(S));                        // S_{l-1}
            k0 = 1.0f + Sp;                                  // lane0: Sp=0 -> 1
            k1 = 1.0f + (S - e1);
        }

        Ah[0] = Ahn[0]; Ah[1] = Ahn[1];
        Al[0] = Aln[0]; Al[1] = Aln[1];
    }

    // --- epilogue: per-block partial, last block folds everything ---------
    if (lane == 63) red4[w] = wgt * k1;      // weighted K[127][127]
    __syncthreads();
    if (tid == 0) {
        float s = red4[0] + red4[1] + red4[2] + red4[3];
        __hip_atomic_store(&partials[gid], s, __ATOMIC_RELEASE,
                           __HIP_MEMORY_SCOPE_AGENT);
        unsigned prev = __hip_atomic_fetch_add(ctr, 1u, __ATOMIC_ACQ_REL,
                                               __HIP_MEMORY_SCOPE_AGENT);
        amLast = (prev == NBLK - 1);
    }
    __syncthreads();
    if (amLast) {
        float acc = 0.f;
        for (int e = tid; e < NBLK; e += 256)
            acc += __hip_atomic_load(&partials[e], __ATOMIC_ACQUIRE,
                                     __HIP_MEMORY_SCOPE_AGENT);
        for (int e = tid; e < AA * DD; e += 256) {
            int aa = e >> 6, d = e & 63;
            float df = X[aa * (MM * DD) + d] - Y[aa * (MM * DD) + d];
            acc = __builtin_fmaf(df * df, 1.0f / 4096.0f, acc);
        }
        #pragma unroll
        for (int off = 32; off > 0; off >>= 1) acc += __shfl_down(acc, off);
        __syncthreads();
        if ((tid & 63) == 0) red4[tid >> 6] = acc;
        __syncthreads();
        if (tid == 0) out[0] = red4[0] + red4[1] + red4[2] + red4[3];
    }
}

extern "C" void kernel_launch(void* const* d_in, const int* in_sizes, int n_in,
                              void* d_out, int out_size, void* d_ws, size_t ws_size,
                              hipStream_t stream) {
    const float* X = (const float*)d_in[0];
    const float* Y = (const float*)d_in[1];
    float* out = (float*)d_out;
    int4*  frag = (int4*)d_ws;
    float* partials = (float*)((char*)d_ws + PART_OFF);
    unsigned* ctr = (unsigned*)((char*)d_ws + PART_OFF + NBLK * sizeof(float));

    hipLaunchKernelGGL(prep_frags, dim3(256), dim3(256), 0, stream, X, Y, frag, ctr);
    hipLaunchKernelGGL(sig_pde, dim3(NBLK), dim3(256), 0, stream,
                       frag, partials, ctr, X, Y, out);
}

// Round 13
// 188.867 us; speedup vs baseline: 1.9803x; 1.1434x over previous
//
#include <hip/hip_runtime.h>

// Problem constants (X, Y: (64, 128, 64) fp32)
#define AA   64
#define MM   128
#define DD   64
#define M1   127
#define CSTR 132                 // inc row stride (words); 132%32=4 -> 2-way banks (free)
#define NXY  1024                // XY gram blocks (all 4096 pairs, 4/block)
#define NTRI 544                 // triangle blocks per symmetric gram (a<=b)
#define NBLK (NXY + 2*NTRI)      // 2112
// ws layout: [0,4MB) frag regions {Xhi,Xlo,Yhi,Ylo} each 1MB =
//   path(64) x tile(8) x ks(2) x lane(64) x int4 ; then NBLK partials.
#define REG_I4 65536             // int4 per 1MB region
#define PART_OFF (4u << 20)

typedef float f32x4 __attribute__((ext_vector_type(4)));
typedef short bf8_t __attribute__((ext_vector_type(8)));

// DPP helper (R4-R6 verified): returns DPP-moved value, 0 in masked lanes.
// Compiler-visible builtin => hazard recognizer inserts wait states AND the
// scheduler can interleave independent work into the chain. R9 LESSON: the
// hand-asm v_add_f32_dpp + s_nop version issued fewer instrs but ran 1.6x
// SLOWER (168 vs 106 us) — forced nop stalls + no interleaving.
template <int CTRL, int RM>
__device__ __forceinline__ float dpp0(float x) {
    return __int_as_float(
        __builtin_amdgcn_update_dpp(0, __float_as_int(x), CTRL, RM, 0xF, false));
}

__device__ __forceinline__ unsigned bf16_rne(float v) {
    unsigned u = __float_as_uint(v);
    return (u + 0x7FFFu + ((u >> 16) & 1u)) >> 16;
}
__device__ __forceinline__ float bf16_tof(unsigned h) {
    return __uint_as_float(h << 16);
}

// ---------------------------------------------------------------------------
// prep: build hi/lo bf16 fragments of dX/dY once, in MFMA fragment order.
// A-frag and B-frag layouts coincide (idx16=lane&15, k=(lane>>4)*8+j).
// Row 127 clamped to 126 (as A: never-scanned row; as B: col masked at lane63).
// ---------------------------------------------------------------------------
__global__ __launch_bounds__(256) void prep_frags(const float* __restrict__ X,
                                                  const float* __restrict__ Y,
                                                  int4* __restrict__ frag) {
    const int tid = threadIdx.x, lane = tid & 63, w = tid >> 6;
    const int W    = blockIdx.x * 4 + w;   // 0..1023
    const int inp  = W >> 9;               // 0: X, 1: Y
    const int p    = (W >> 3) & 63;
    const int tile = W & 7;
    const float* S = (inp ? Y : X) + p * (MM * DD);
    int i = tile * 16 + (lane & 15);
    if (i > 126) i = 126;
    const int d0 = (lane >> 4) << 3;

    int4* hi = frag + (inp * 2 + 0) * REG_I4;
    int4* lo = frag + (inp * 2 + 1) * REG_I4;
    const int base = p * 1024 + tile * 128 + lane;

    #pragma unroll
    for (int ks = 0; ks < 2; ++ks) {
        const float* r0 = S + i * DD + ks * 32 + d0;
        const float* r1 = r0 + DD;
        float4 a0 = *(const float4*)r0;
        float4 a1 = *(const float4*)(r0 + 4);
        float4 c0 = *(const float4*)r1;
        float4 c1 = *(const float4*)(r1 + 4);
        float v[8] = {c0.x - a0.x, c0.y - a0.y, c0.z - a0.z, c0.w - a0.w,
                      c1.x - a1.x, c1.y - a1.y, c1.z - a1.z, c1.w - a1.w};
        unsigned hs[8], ls[8];
        #pragma unroll
        for (int e = 0; e < 8; ++e) {
            hs[e] = bf16_rne(v[e]);
            ls[e] = bf16_rne(v[e] - bf16_tof(hs[e]));
        }
        int4 h, l;
        h.x = hs[0] | (hs[1] << 16); h.y = hs[2] | (hs[3] << 16);
        h.z = hs[4] | (hs[5] << 16); h.w = hs[6] | (hs[7] << 16);
        l.x = ls[0] | (ls[1] << 16); l.y = ls[2] | (ls[3] << 16);
        l.z = ls[4] | (ls[5] << 16); l.w = ls[6] | (ls[7] << 16);
        hi[base + ks * 64] = h;
        lo[base + ks * 64] = l;
    }
}

// ---------------------------------------------------------------------------
// PDE kernel. gid < 1024: XY gram (all pairs). Else triangle blocks for
// XX / YY (a<=b; weight 2 off-diag, 1 diag, 0 ragged).
// Occupancy: incS is 8 rows (half-strip) instead of 16 -> LDS ~49.7 KB ->
// 3 blocks/CU (was 2). Each strip: MFMA 16 rows into regs, then twice
// {owning half-lanes write 8 rows -> scan 8 rows}. Same-wave LDS write->read
// ordering (no barrier) — relied on since R5.
// Epilogue: plain per-block store (R6-proven); no cross-block sync — the
// R10-R12 last-block-fold variant hit repeated container failures, so the
// inter-block atomic pattern is removed as a precaution.
// ---------------------------------------------------------------------------
__global__ __launch_bounds__(256, 3)
void sig_pde(const int4* __restrict__ frag, float* __restrict__ partials) {
    const int tid = threadIdx.x, lane = tid & 63, w = tid >> 6;
    const int gid = blockIdx.x;

    int a, b, ain, bin;
    float wgt;
    if (gid < NXY) {
        b = gid >> 4; a = ((gid & 15) << 2) | w;
        ain = 0; bin = 1;
        wgt = -2.0f / 4096.0f;
    } else {
        int t = gid - NXY;
        int inp = 0;
        if (t >= NTRI) { t -= NTRI; inp = 1; }
        int q = (int)((__builtin_sqrtf((float)(2 * t + 1)) - 1.0f) * 0.5f);
        while (2 * (q + 1) * (q + 2) <= t) ++q;
        while (q > 0 && 2 * q * (q + 1) > t) --q;
        int r  = t - 2 * q * (q + 1);
        int i  = r / (q + 1);
        int ag = r - i * (q + 1);
        b = 4 * q + i; a = 4 * ag + w;
        ain = bin = inp;
        wgt = (a < b) ? (2.0f / 4096.0f) : ((a == b) ? (1.0f / 4096.0f) : 0.0f);
    }

    __shared__ int4  Bh[1024], Bl[1024];     // 32 KB B fragments (hi/lo)
    __shared__ float incS[4][8 * CSTR];      // 16.9 KB per-wave half-strips
    __shared__ float red4[4];

    // --- stage this block's B fragment set (flat 32 KB copy) --------------
    {
        const int4* Bhg = frag + (bin * 2 + 0) * REG_I4 + b * 1024;
        const int4* Blg = frag + (bin * 2 + 1) * REG_I4 + b * 1024;
        #pragma unroll
        for (int c = 0; c < 4; ++c) {
            int idx = c * 256 + tid;
            Bh[idx] = Bhg[idx];
            Bl[idx] = Blg[idx];
        }
    }
    __syncthreads();

    const int4* Ahg = frag + (ain * 2 + 0) * REG_I4 + a * 1024;
    const int4* Alg = frag + (ain * 2 + 1) * REG_I4 + a * 1024;

    int4 Ah[2], Al[2], Ahn[2], Aln[2];
    Ah[0] = Ahg[lane];      Ah[1] = Ahg[64 + lane];
    Al[0] = Alg[lane];      Al[1] = Alg[64 + lane];

    float k0 = 1.0f, k1 = 1.0f;              // K[2l], K[2l+1] of current row
    float* incW = &incS[w][0];
    const int c2l = lane << 1;
    const int r0w = (lane >> 4) << 2, c0w = lane & 15;
    const int rloc = r0w & 7;                // row within half-strip buffer
    const int myhalf = r0w >> 3;             // which half this lane's rows go to

    for (int strip = 0; strip < 8; ++strip) {
        if (strip < 7) {                     // prefetch next strip's A frags
            int off = (strip + 1) * 128 + lane;
            Ahn[0] = Ahg[off]; Ahn[1] = Ahg[off + 64];
            Aln[0] = Alg[off]; Aln[1] = Alg[off + 64];
        }

        f32x4 acc[8];
        #pragma unroll
        for (int t = 0; t < 8; ++t) acc[t] = (f32x4){0.f, 0.f, 0.f, 0.f};
        #pragma unroll
        for (int s = 0; s < 2; ++s) {
            bf8_t ah = __builtin_bit_cast(bf8_t, Ah[s]);
            bf8_t al = __builtin_bit_cast(bf8_t, Al[s]);
            #pragma unroll
            for (int t = 0; t < 8; ++t) {
                int fb = (t * 2 + s) * 64 + lane;
                bf8_t bh = *(const bf8_t*)&Bh[fb];
                bf8_t bl = *(const bf8_t*)&Bl[fb];
                acc[t] = __builtin_amdgcn_mfma_f32_16x16x32_bf16(ah, bh, acc[t], 0, 0, 0);
                acc[t] = __builtin_amdgcn_mfma_f32_16x16x32_bf16(ah, bl, acc[t], 0, 0, 0);
                acc[t] = __builtin_amdgcn_mfma_f32_16x16x32_bf16(al, bh, acc[t], 0, 0, 0);
            }
        }

        // two half-strips: owning lanes write 8 rows, all lanes scan them
        #pragma unroll
        for (int h = 0; h < 2; ++h) {
            if (myhalf == h) {
                #pragma unroll
                for (int t = 0; t < 8; ++t) {
                    float* pb = incW + rloc * CSTR + (t << 4) + c0w;
                    pb[0]        = acc[t][0];
                    pb[CSTR]     = acc[t][1];
                    pb[2 * CSTR] = acc[t][2];
                    pb[3 * CSTR] = acc[t][3];
                }
            }
            const int nrows = (strip == 7 && h == 1) ? 7 : 8;
            for (int r = 0; r < nrows; ++r) {
                float2 sv = *(const float2*)(incW + r * CSTR + c2l);
                float s0 = sv.x, s1 = sv.y;
                float kp2 = dpp0<0x130, 0xF>(k0);            // K[2l+2] (wf_sl1)
                float e0  = __builtin_fmaf(k0, s0, k1 - k0);  // delta[2l]
                float e1  = __builtin_fmaf(k1, s1, kp2 - k1); // delta[2l+1]
                e1 = (lane < 63) ? e1 : 0.0f;
                float S = e0 + e1;
                S += dpp0<0x111, 0xF>(S);                    // row_shr:1
                S += dpp0<0x112, 0xF>(S);                    // row_shr:2
                S += dpp0<0x114, 0xF>(S);                    // row_shr:4
                S += dpp0<0x118, 0xF>(S);                    // row_shr:8
                S += dpp0<0x142, 0xA>(S);                    // row_bcast:15
                S += dpp0<0x143, 0xC>(S);                    // row_bcast:31
                float Sp = dpp0<0x138, 0xF>(S);              // S_{l-1} (wf_sr1)
                k0 = 1.0f + Sp;                              // lane0: Sp=0 -> 1
                k1 = 1.0f + (S - e1);
            }
        }

        Ah[0] = Ahn[0]; Ah[1] = Ahn[1];
        Al[0] = Aln[0]; Al[1] = Aln[1];
    }

    // --- epilogue: plain per-block partial store (no atomics) -------------
    if (lane == 63) red4[w] = wgt * k1;      // weighted K[127][127]
    __syncthreads();
    if (tid == 0)
        partials[gid] = red4[0] + red4[1] + red4[2] + red4[3];
}

// ---------------------------------------------------------------------------
// final: out[0] = sum(partials) + mean((X0-Y0)^2) (msq folded with 1/4096).
// ---------------------------------------------------------------------------
__global__ void final_sum(const float* __restrict__ X, const float* __restrict__ Y,
                          const float* __restrict__ partials, float* __restrict__ out) {
    __shared__ float red[4];
    int tid = threadIdx.x;                   // 256 threads
    float acc = 0.f;
    for (int e = tid; e < NBLK; e += 256) acc += partials[e];
    for (int e = tid; e < AA * DD; e += 256) {
        int aa = e >> 6, d = e & 63;
        float df = X[aa * (MM * DD) + d] - Y[aa * (MM * DD) + d];
        acc = __builtin_fmaf(df * df, 1.0f / 4096.0f, acc);
    }
    #pragma unroll
    for (int off = 32; off > 0; off >>= 1) acc += __shfl_down(acc, off);
    if ((tid & 63) == 0) red[tid >> 6] = acc;
    __syncthreads();
    if (tid == 0) out[0] = red[0] + red[1] + red[2] + red[3];
}

extern "C" void kernel_launch(void* const* d_in, const int* in_sizes, int n_in,
                              void* d_out, int out_size, void* d_ws, size_t ws_size,
                              hipStream_t stream) {
    const float* X = (const float*)d_in[0];
    const float* Y = (const float*)d_in[1];
    float* out = (float*)d_out;
    int4*  frag = (int4*)d_ws;
    float* partials = (float*)((char*)d_ws + PART_OFF);

    hipLaunchKernelGGL(prep_frags, dim3(256), dim3(256), 0, stream, X, Y, frag);
    hipLaunchKernelGGL(sig_pde, dim3(NBLK), dim3(256), 0, stream, frag, partials);
    hipLaunchKernelGGL(final_sum, dim3(1), dim3(256), 0, stream, X, Y, partials, out);
}

// Round 14
// 165.780 us; speedup vs baseline: 2.2561x; 1.1393x over previous
//
#include <hip/hip_runtime.h>

// Problem constants (X, Y: (64, 128, 64) fp32)
#define AA   64
#define MM   128
#define DD   64
#define M1   127
#define CSTR 132                 // inc row stride (words); 132%32=4 -> 2-way banks (free)
#define NXY  1024                // XY gram blocks (all 4096 pairs, 4/block)
#define NTRI 544                 // triangle blocks per symmetric gram (a<=b)
#define NBLK (NXY + 2*NTRI)      // 2112
// ws layout: [0,4MB) frag regions {Xhi,Xlo,Yhi,Ylo} each 1MB =
//   path(64) x tile(8) x ks(2) x lane(64) x int4 ; then NBLK partials.
#define REG_I4 65536             // int4 per 1MB region
#define PART_OFF (4u << 20)

typedef float f32x4 __attribute__((ext_vector_type(4)));
typedef short bf8_t __attribute__((ext_vector_type(8)));

// DPP helper (R4-R6 verified): returns DPP-moved value, 0 in masked lanes.
// Compiler-visible builtin => hazard recognizer inserts wait states AND the
// scheduler can interleave independent work into the chain (hand-asm variant
// was 1.6x slower — R9).
template <int CTRL, int RM>
__device__ __forceinline__ float dpp0(float x) {
    return __int_as_float(
        __builtin_amdgcn_update_dpp(0, __float_as_int(x), CTRL, RM, 0xF, false));
}

__device__ __forceinline__ unsigned bf16_rne(float v) {
    unsigned u = __float_as_uint(v);
    return (u + 0x7FFFu + ((u >> 16) & 1u)) >> 16;
}
__device__ __forceinline__ float bf16_tof(unsigned h) {
    return __uint_as_float(h << 16);
}

// ---------------------------------------------------------------------------
// prep: build hi/lo bf16 fragments of dX/dY once, in MFMA fragment order.
// A-frag and B-frag layouts coincide (idx16=lane&15, k=(lane>>4)*8+j).
// Row 127 clamped to 126 (as A: never-scanned row; as B: col masked at lane63).
// ---------------------------------------------------------------------------
__global__ __launch_bounds__(256) void prep_frags(const float* __restrict__ X,
                                                  const float* __restrict__ Y,
                                                  int4* __restrict__ frag) {
    const int tid = threadIdx.x, lane = tid & 63, w = tid >> 6;
    const int W    = blockIdx.x * 4 + w;   // 0..1023
    const int inp  = W >> 9;               // 0: X, 1: Y
    const int p    = (W >> 3) & 63;
    const int tile = W & 7;
    const float* S = (inp ? Y : X) + p * (MM * DD);
    int i = tile * 16 + (lane & 15);
    if (i > 126) i = 126;
    const int d0 = (lane >> 4) << 3;

    int4* hi = frag + (inp * 2 + 0) * REG_I4;
    int4* lo = frag + (inp * 2 + 1) * REG_I4;
    const int base = p * 1024 + tile * 128 + lane;

    #pragma unroll
    for (int ks = 0; ks < 2; ++ks) {
        const float* r0 = S + i * DD + ks * 32 + d0;
        const float* r1 = r0 + DD;
        float4 a0 = *(const float4*)r0;
        float4 a1 = *(const float4*)(r0 + 4);
        float4 c0 = *(const float4*)r1;
        float4 c1 = *(const float4*)(r1 + 4);
        float v[8] = {c0.x - a0.x, c0.y - a0.y, c0.z - a0.z, c0.w - a0.w,
                      c1.x - a1.x, c1.y - a1.y, c1.z - a1.z, c1.w - a1.w};
        unsigned hs[8], ls[8];
        #pragma unroll
        for (int e = 0; e < 8; ++e) {
            hs[e] = bf16_rne(v[e]);
            ls[e] = bf16_rne(v[e] - bf16_tof(hs[e]));
        }
        int4 h, l;
        h.x = hs[0] | (hs[1] << 16); h.y = hs[2] | (hs[3] << 16);
        h.z = hs[4] | (hs[5] << 16); h.w = hs[6] | (hs[7] << 16);
        l.x = ls[0] | (ls[1] << 16); l.y = ls[2] | (ls[3] << 16);
        l.z = ls[4] | (ls[5] << 16); l.w = ls[6] | (ls[7] << 16);
        hi[base + ks * 64] = h;
        lo[base + ks * 64] = l;
    }
}

// ---------------------------------------------------------------------------
// PDE kernel. gid < 1024: XY gram (all pairs). Else triangle blocks for
// XX / YY (a<=b; weight 2 off-diag, 1 diag, 0 ragged).
// Occupancy: half-strip incS -> LDS 49.7 KB -> 3 blocks/CU (LDS-limited).
// LAUNCH_BOUNDS RULE (R1/R2/R13 measured): declared min-waves w => allocator
// budgets ~512/(2w) VGPRs. Kernel needs ~104 (R9). w=3 -> 84 -> spill
// (R13: 82 MB scratch writes, 137 us). w=2 -> 128 >= 104 -> no spill, and
// occupancy is then LDS-limited at 3 blocks/CU anyway.
// Epilogue: plain per-block store; no cross-block sync.
// ---------------------------------------------------------------------------
__global__ __launch_bounds__(256, 2)
void sig_pde(const int4* __restrict__ frag, float* __restrict__ partials) {
    const int tid = threadIdx.x, lane = tid & 63, w = tid >> 6;
    const int gid = blockIdx.x;

    int a, b, ain, bin;
    float wgt;
    if (gid < NXY) {
        b = gid >> 4; a = ((gid & 15) << 2) | w;
        ain = 0; bin = 1;
        wgt = -2.0f / 4096.0f;
    } else {
        int t = gid - NXY;
        int inp = 0;
        if (t >= NTRI) { t -= NTRI; inp = 1; }
        int q = (int)((__builtin_sqrtf((float)(2 * t + 1)) - 1.0f) * 0.5f);
        while (2 * (q + 1) * (q + 2) <= t) ++q;
        while (q > 0 && 2 * q * (q + 1) > t) --q;
        int r  = t - 2 * q * (q + 1);
        int i  = r / (q + 1);
        int ag = r - i * (q + 1);
        b = 4 * q + i; a = 4 * ag + w;
        ain = bin = inp;
        wgt = (a < b) ? (2.0f / 4096.0f) : ((a == b) ? (1.0f / 4096.0f) : 0.0f);
    }

    __shared__ int4  Bh[1024], Bl[1024];     // 32 KB B fragments (hi/lo)
    __shared__ float incS[4][8 * CSTR];      // 16.9 KB per-wave half-strips
    __shared__ float red4[4];

    // --- stage this block's B fragment set (flat 32 KB copy) --------------
    {
        const int4* Bhg = frag + (bin * 2 + 0) * REG_I4 + b * 1024;
        const int4* Blg = frag + (bin * 2 + 1) * REG_I4 + b * 1024;
        #pragma unroll
        for (int c = 0; c < 4; ++c) {
            int idx = c * 256 + tid;
            Bh[idx] = Bhg[idx];
            Bl[idx] = Blg[idx];
        }
    }
    __syncthreads();

    const int4* Ahg = frag + (ain * 2 + 0) * REG_I4 + a * 1024;
    const int4* Alg = frag + (ain * 2 + 1) * REG_I4 + a * 1024;

    int4 Ah[2], Al[2], Ahn[2], Aln[2];
    Ah[0] = Ahg[lane];      Ah[1] = Ahg[64 + lane];
    Al[0] = Alg[lane];      Al[1] = Alg[64 + lane];

    float k0 = 1.0f, k1 = 1.0f;              // K[2l], K[2l+1] of current row
    float* incW = &incS[w][0];
    const int c2l = lane << 1;
    const int r0w = (lane >> 4) << 2, c0w = lane & 15;
    const int rloc = r0w & 7;                // row within half-strip buffer
    const int myhalf = r0w >> 3;             // which half this lane's rows go to

    for (int strip = 0; strip < 8; ++strip) {
        if (strip < 7) {                     // prefetch next strip's A frags
            int off = (strip + 1) * 128 + lane;
            Ahn[0] = Ahg[off]; Ahn[1] = Ahg[off + 64];
            Aln[0] = Alg[off]; Aln[1] = Alg[off + 64];
        }

        f32x4 acc[8];
        #pragma unroll
        for (int t = 0; t < 8; ++t) acc[t] = (f32x4){0.f, 0.f, 0.f, 0.f};
        #pragma unroll
        for (int s = 0; s < 2; ++s) {
            bf8_t ah = __builtin_bit_cast(bf8_t, Ah[s]);
            bf8_t al = __builtin_bit_cast(bf8_t, Al[s]);
            #pragma unroll
            for (int t = 0; t < 8; ++t) {
                int fb = (t * 2 + s) * 64 + lane;
                bf8_t bh = *(const bf8_t*)&Bh[fb];
                bf8_t bl = *(const bf8_t*)&Bl[fb];
                acc[t] = __builtin_amdgcn_mfma_f32_16x16x32_bf16(ah, bh, acc[t], 0, 0, 0);
                acc[t] = __builtin_amdgcn_mfma_f32_16x16x32_bf16(ah, bl, acc[t], 0, 0, 0);
                acc[t] = __builtin_amdgcn_mfma_f32_16x16x32_bf16(al, bh, acc[t], 0, 0, 0);
            }
        }

        // two half-strips: owning lanes write 8 rows, all lanes scan them
        #pragma unroll
        for (int h = 0; h < 2; ++h) {
            if (myhalf == h) {
                #pragma unroll
                for (int t = 0; t < 8; ++t) {
                    float* pb = incW + rloc * CSTR + (t << 4) + c0w;
                    pb[0]        = acc[t][0];
                    pb[CSTR]     = acc[t][1];
                    pb[2 * CSTR] = acc[t][2];
                    pb[3 * CSTR] = acc[t][3];
                }
            }
            const int nrows = (strip == 7 && h == 1) ? 7 : 8;
            for (int r = 0; r < nrows; ++r) {
                float2 sv = *(const float2*)(incW + r * CSTR + c2l);
                float s0 = sv.x, s1 = sv.y;
                float kp2 = dpp0<0x130, 0xF>(k0);            // K[2l+2] (wf_sl1)
                float e0  = __builtin_fmaf(k0, s0, k1 - k0);  // delta[2l]
                float e1  = __builtin_fmaf(k1, s1, kp2 - k1); // delta[2l+1]
                e1 = (lane < 63) ? e1 : 0.0f;
                float S = e0 + e1;
                S += dpp0<0x111, 0xF>(S);                    // row_shr:1
                S += dpp0<0x112, 0xF>(S);                    // row_shr:2
                S += dpp0<0x114, 0xF>(S);                    // row_shr:4
                S += dpp0<0x118, 0xF>(S);                    // row_shr:8
                S += dpp0<0x142, 0xA>(S);                    // row_bcast:15
                S += dpp0<0x143, 0xC>(S);                    // row_bcast:31
                float Sp = dpp0<0x138, 0xF>(S);              // S_{l-1} (wf_sr1)
                k0 = 1.0f + Sp;                              // lane0: Sp=0 -> 1
                k1 = 1.0f + (S - e1);
            }
        }

        Ah[0] = Ahn[0]; Ah[1] = Ahn[1];
        Al[0] = Aln[0]; Al[1] = Aln[1];
    }

    // --- epilogue: plain per-block partial store (no atomics) -------------
    if (lane == 63) red4[w] = wgt * k1;      // weighted K[127][127]
    __syncthreads();
    if (tid == 0)
        partials[gid] = red4[0] + red4[1] + red4[2] + red4[3];
}

// ---------------------------------------------------------------------------
// final: out[0] = sum(partials) + mean((X0-Y0)^2) (msq folded with 1/4096).
// ---------------------------------------------------------------------------
__global__ void final_sum(const float* __restrict__ X, const float* __restrict__ Y,
                          const float* __restrict__ partials, float* __restrict__ out) {
    __shared__ float red[4];
    int tid = threadIdx.x;                   // 256 threads
    float acc = 0.f;
    for (int e = tid; e < NBLK; e += 256) acc += partials[e];
    for (int e = tid; e < AA * DD; e += 256) {
        int aa = e >> 6, d = e & 63;
        float df = X[aa * (MM * DD) + d] - Y[aa * (MM * DD) + d];
        acc = __builtin_fmaf(df * df, 1.0f / 4096.0f, acc);
    }
    #pragma unroll
    for (int off = 32; off > 0; off >>= 1) acc += __shfl_down(acc, off);
    if ((tid & 63) == 0) red[tid >> 6] = acc;
    __syncthreads();
    if (tid == 0) out[0] = red[0] + red[1] + red[2] + red[3];
}

extern "C" void kernel_launch(void* const* d_in, const int* in_sizes, int n_in,
                              void* d_out, int out_size, void* d_ws, size_t ws_size,
                              hipStream_t stream) {
    const float* X = (const float*)d_in[0];
    const float* Y = (const float*)d_in[1];
    float* out = (float*)d_out;
    int4*  frag = (int4*)d_ws;
    float* partials = (float*)((char*)d_ws + PART_OFF);

    hipLaunchKernelGGL(prep_frags, dim3(256), dim3(256), 0, stream, X, Y, frag);
    hipLaunchKernelGGL(sig_pde, dim3(NBLK), dim3(256), 0, stream, frag, partials);
    hipLaunchKernelGGL(final_sum, dim3(1), dim3(256), 0, stream, X, Y, partials, out);
}